// Round 3
// baseline (10748.354 us; speedup 1.0000x reference)
//
#include <hip/hip_runtime.h>
#include <math.h>

// Problem constants (match reference)
#define B_   1024
#define NC   100
#define NN   101          // N = NC + 1
#define E_   128
#define T_   202          // 2*N
#define NEGV   -1.0e9
#define NEGVF  -1.0e9f
#define GAPTHR 4.0e-3f    // fp32-path error bound ~3e-4 -> 13x margin
#define INVSQE 0.08838834764831845f
#define INVSQED 0.08838834764831845

// ---------------------------------------------------------------------------
// kernel 0: M = Wk2 @ Wout^T (128x128) into ws as fp64 (fallback) + fp32 (fast)
// ---------------------------------------------------------------------------
__global__ void k_weights(const float* __restrict__ Wk2,
                          const float* __restrict__ Wout,
                          double* __restrict__ M64,
                          float* __restrict__ M32) {
    int g = blockIdx.x;   // 0..127
    int e = threadIdx.x;  // 0..127
    const float* w2 = Wk2 + g * E_;
    const float* wo = Wout + e * E_;
    double acc = 0.0;
#pragma unroll 8
    for (int f = 0; f < E_; ++f) acc += (double)w2[f] * (double)wo[f];
    M64[g * E_ + e] = acc;
    M32[g * E_ + e] = (float)acc;
}

// ---------------------------------------------------------------------------
// Main decoder. 1 block / batch element, 512 threads (8 waves), 2 blocks/CU.
// Fast path fp32 (5 barriers/step); exact fp64 fallback when top-2 pre-tanh
// logit gap < GAPTHR (rare). State (D, masks) bit-exact fp32 vs reference.
// ---------------------------------------------------------------------------
__global__ __launch_bounds__(512, 4)
void k_decode(const float* __restrict__ depot_xy,
              const float* __restrict__ customer_xy,
              const float* __restrict__ demand,
              const float* __restrict__ node_emb,
              const float* __restrict__ graph_emb,
              const float* __restrict__ Wk1,
              const float* __restrict__ Wv,
              const float* __restrict__ Wq_fixed,
              const float* __restrict__ Wq_step,
              const double* __restrict__ M64,
              const float* __restrict__ M32,
              float* __restrict__ out)          // [2*B]: cost then ll
{
    // Kstep = emb @ Wq_step[:128]  (fp32, per-node rows)
    __shared__ float sKs[NN * E_];              // 51.7 KB
    // Union scratch: fast fp32 buffers overlay fallback fp64 buffers (17.8 KB)
    __shared__ double sU[2224];
    __shared__ double sQfix64[E_];
    __shared__ double sWqD64[E_];
    __shared__ float  sQfix32[E_];
    __shared__ float  sWqD32[E_];
    __shared__ float  sCoord[2 * NN];
    __shared__ float  sDem[NC];
    __shared__ float  sD;
    __shared__ double sCost, sLL;
    __shared__ float  sPosX, sPosY;
    __shared__ int    sPrev, sMaskDepot, sTrig, sOvf;
    __shared__ unsigned long long sVis0, sVis1;

    // fast fp32 views
    float* fQ1   = (float*)sU;          // [128]
    float* fSc   = (float*)sU + 128;    // [8][104] exp-scores (pads k=101..103)
    float* fPart = (float*)sU + 960;    // [4][128] glimpse partials
    float* fPx   = (float*)sU + 1472;   // [4][128] logit partials
    float* fPs   = (float*)sU + 1984;   // [4][8]   per-(chunk,head) exp sums
    // fallback fp64 views
    double* dUZ = sU;                   // [128][8] u1 then z
    double* dSc = sU + 1024;            // [8][101] scores -> weights
    double* dQ1 = sU + 1832;            // [128] q1, later xd[101]
    double* dGl = sU + 1960;            // [128]
    double* dVg = sU + 2088;            // [128]

    const int b      = blockIdx.x;
    const int tid    = threadIdx.x;
    const int k_lane = tid & 127;
    const int q2     = tid >> 7;                   // 0..3 (uniform per wave)
    const int e0     = __builtin_amdgcn_readfirstlane(q2) * 32;

    const float* emb = node_emb + (size_t)b * NN * E_;

    // ---------------- prologue ----------------
    if (tid < E_) {
        const float* ge = graph_emb + (size_t)b * E_;
        double acc = 0.0;
        for (int g = 0; g < E_; ++g)
            acc += (double)ge[g] * (double)Wq_fixed[g * E_ + tid];
        sQfix64[tid] = acc;
        sQfix32[tid] = (float)acc;
        sWqD64[tid]  = (double)Wq_step[128 * E_ + tid];
        sWqD32[tid]  = Wq_step[128 * E_ + tid];
    }
    if (tid < 2 * NN) {
        int k = tid >> 1, xy = tid & 1;
        sCoord[tid] = (k == 0) ? depot_xy[(size_t)b * 2 + xy]
                               : customer_xy[((size_t)b * NC + (k - 1)) * 2 + xy];
    }
    if (tid < NC) sDem[tid] = demand[(size_t)b * NC + tid];
    if (tid == 0) {
        sD = 1.f; sPrev = 0; sVis0 = 0ull; sVis1 = 0ull;
        sMaskDepot = 1; sCost = 0.0; sLL = 0.0; sTrig = 0; sOvf = 0;
        sPosX = depot_xy[(size_t)b * 2 + 0];
        sPosY = depot_xy[(size_t)b * 2 + 1];
    }

    // Kstep into LDS (fp32, float4 over columns)
    for (int idx = tid; idx < NN * 32; idx += 512) {
        int k  = idx >> 5;
        int e4 = (idx & 31) * 4;
        const float* er = emb + (size_t)k * E_;
        float4 a = {0.f, 0.f, 0.f, 0.f};
        for (int g = 0; g < E_; ++g) {
            float eg = er[g];
            float4 w = *(const float4*)(Wq_step + (size_t)g * E_ + e4);
            a.x += eg * w.x; a.y += eg * w.y; a.z += eg * w.z; a.w += eg * w.w;
        }
        *(float4*)(sKs + (size_t)k * E_ + e4) = a;
    }

    // K1, K2t chunks (32 cols) into registers (fp32)
    float rK1[32], rK2[32];
#pragma unroll
    for (int j = 0; j < 32; ++j) { rK1[j] = 0.f; rK2[j] = 0.f; }
    if (k_lane < NN) {
        const float* er = emb + (size_t)k_lane * E_;
        for (int g = 0; g < E_; ++g) {
            float eg = er[g];
            const float* w1 = Wk1 + (size_t)g * E_ + e0;
            const float* mm = M32 + (size_t)g * E_ + e0;
#pragma unroll
            for (int j = 0; j < 32; ++j) {
                rK1[j] += eg * w1[j];
                rK2[j] += eg * mm[j];
            }
        }
    }
    // V chunk into registers: thread (e=k_lane, q2) holds V[kb+j][e]
    float rV[26];
    {
        int kb = q2 * 26;
        int e  = k_lane;
#pragma unroll
        for (int j = 0; j < 26; ++j) rV[j] = 0.f;
        for (int g = 0; g < E_; ++g) {
            float wv = Wv[(size_t)g * E_ + e];
#pragma unroll
            for (int j = 0; j < 26; ++j) {
                int k = kb + j;
                if (k < NN) rV[j] += emb[(size_t)k * E_ + g] * wv;
            }
        }
    }
    __syncthreads();

    // ---------------- sequential decode loop ----------------
    for (int t = 0; t < T_; ++t) {
        // ---- A: q1 (scaled by 1/sqrt(16)=0.25) ----
        if (tid < E_) {
            if (tid == 0) sOvf = 0;
            fQ1[tid] = (sQfix32[tid] + sKs[sPrev * E_ + tid] + sD * sWqD32[tid]) * 0.25f;
        }
        __syncthreads();

        // ---- B: exp-scores (no max subtraction; masked -> 0) ----
        if (k_lane < 104) {
            bool mk;
            if (k_lane == 0)      mk = (sMaskDepot != 0);
            else if (k_lane >= NN) mk = true;
            else {
                int c = k_lane - 1;
                bool vis = (c < 64) ? ((sVis0 >> c) & 1ull)
                                    : ((sVis1 >> (c - 64)) & 1ull);
                mk = vis || (sDem[c] > sD);
            }
            int h0 = 2 * q2;
            if (mk) {
                fSc[h0 * 104 + k_lane]       = 0.f;
                fSc[(h0 + 1) * 104 + k_lane] = 0.f;
            } else {
                float s0 = 0.f, s1 = 0.f;
#pragma unroll
                for (int j = 0; j < 16; ++j) s0 += rK1[j]      * fQ1[e0 + j];
#pragma unroll
                for (int j = 0; j < 16; ++j) s1 += rK1[16 + j] * fQ1[e0 + 16 + j];
                if (s0 > 80.f || s1 > 80.f) { sOvf = 1; s0 = fminf(s0, 80.f); s1 = fminf(s1, 80.f); }
                fSc[h0 * 104 + k_lane]       = expf(s0);
                fSc[(h0 + 1) * 104 + k_lane] = expf(s1);
            }
        }
        __syncthreads();

        // ---- C: glimpse partials + per-(chunk,head) exp sums ----
        {
            int e = k_lane, h = e >> 4, kb = q2 * 26;
            float p = 0.f, ssum = 0.f;
#pragma unroll
            for (int j = 0; j < 26; ++j) {
                float w = fSc[h * 104 + kb + j];   // pads are 0
                p    += w * rV[j];
                ssum += w;
            }
            fPart[q2 * E_ + e] = p;
            if ((e & 15) == 0) fPs[q2 * 8 + h] = ssum;
        }
        __syncthreads();

        // ---- D: logit partials (normalization folded in) ----
        if (k_lane < NN) {
            int h0 = 2 * q2;
            float sA = fPs[h0] + fPs[8 + h0] + fPs[16 + h0] + fPs[24 + h0];
            float sB = fPs[h0 + 1] + fPs[8 + h0 + 1] + fPs[16 + h0 + 1] + fPs[24 + h0 + 1];
            float invA = 1.f / sA, invB = 1.f / sB;
            float xa = 0.f, xb = 0.f;
#pragma unroll
            for (int j = 0; j < 16; ++j) {
                int e = e0 + j;
                float gl = fPart[e] + fPart[128 + e] + fPart[256 + e] + fPart[384 + e];
                xa += rK2[j] * gl;
            }
#pragma unroll
            for (int j = 16; j < 32; ++j) {
                int e = e0 + j;
                float gl = fPart[e] + fPart[128 + e] + fPart[256 + e] + fPart[384 + e];
                xb += rK2[j] * gl;
            }
            fPx[q2 * E_ + k_lane] = xa * invA + xb * invB;
        }
        __syncthreads();

        // ---- E: top-2 argmax (pre-tanh), gap test, commit-or-trigger ----
        if (tid < 64) {
            int kA = tid, kB = tid + 64;
            float xA = (fPx[kA] + fPx[128 + kA] + fPx[256 + kA] + fPx[384 + kA]) * INVSQE;
            bool mk1;
            if (kA == 0) mk1 = (sMaskDepot != 0);
            else {
                int c = kA - 1;
                bool vis = (c < 64) ? ((sVis0 >> c) & 1ull) : ((sVis1 >> (c - 64)) & 1ull);
                mk1 = vis || (sDem[c] > sD);
            }
            float xB = -3.0e38f; bool mk2 = true;
            if (kB < NN) {
                xB = (fPx[kB] + fPx[128 + kB] + fPx[256 + kB] + fPx[384 + kB]) * INVSQE;
                int c = kB - 1;
                bool vis = (c < 64) ? ((sVis0 >> c) & 1ull) : ((sVis1 >> (c - 64)) & 1ull);
                mk2 = vis || (sDem[c] > sD);
            }
            float a1v = mk1 ? -3.0e38f : xA;
            float a2v = mk2 ? -3.0e38f : xB;
            float m1, m2; int mi;
            if (a2v > a1v) { m1 = a2v; m2 = a1v; mi = kB; }
            else           { m1 = a1v; m2 = a2v; mi = kA; }
            float ls = 0.f;
            if (!mk1)              ls += expf(10.f * tanhf(xA));
            if (kB < NN && !mk2)   ls += expf(10.f * tanhf(xB));
#pragma unroll
            for (int off = 32; off > 0; off >>= 1) {
                float om1 = __shfl_xor(m1, off);
                float om2 = __shfl_xor(m2, off);
                float os  = __shfl_xor(ls, off);
                int   omi = __shfl_xor(mi, off);
                ls += os;
                if (om1 > m1 || (om1 == m1 && omi < mi)) {
                    m2 = fmaxf(m1, om2); m1 = om1; mi = omi;
                } else {
                    m2 = fmaxf(m2, om1);
                }
            }
            if (tid == 0) {
                float gap = m1 - m2;
                bool trig = !(gap >= GAPTHR) || (sOvf != 0);   // NaN-safe
                if (trig) {
                    sTrig = 1;
                } else {
                    float lsel = 10.f * tanhf(m1);
                    float logp = lsel - logf(ls);
                    int nxt = mi;
                    sLL += (double)logp;
                    bool isdep = (nxt == 0);
                    if (isdep) {
                        sD = 1.0f;
                    } else {
                        int c = nxt - 1;
                        sD = sD - sDem[c];
                        if (c < 64) sVis0 |= (1ull << c);
                        else        sVis1 |= (1ull << (c - 64));
                    }
                    bool allv = (sVis0 == 0xFFFFFFFFFFFFFFFFull) &&
                                (sVis1 == 0x0000000FFFFFFFFFull);
                    sMaskDepot = (isdep && !allv) ? 1 : 0;
                    sPrev = nxt;
                    float cx = sCoord[2 * nxt], cy = sCoord[2 * nxt + 1];
                    double dx = (double)cx - (double)sPosX;
                    double dy = (double)cy - (double)sPosY;
                    sCost += sqrt(dx * dx + dy * dy + 1e-10);
                    sPosX = cx; sPosY = cy;
                }
            }
        }
        __syncthreads();

        // ---- Fallback: exact fp64 recompute of this step (rare) ----
        if (sTrig) {
            // F0: q1d
            if (tid < E_) {
                const float* ep = emb + (size_t)sPrev * E_;
                double ks = 0.0;
                for (int g = 0; g < E_; ++g)
                    ks += (double)ep[g] * (double)Wq_step[(size_t)g * E_ + tid];
                dQ1[tid] = (sQfix64[tid] + ks + (double)sD * sWqD64[tid]) * 0.25;
            }
            __syncthreads();
            // F1: u1[g][h]
            for (int idx = tid; idx < 1024; idx += 512) {
                int g = idx >> 3, h = idx & 7;
                double u = 0.0;
#pragma unroll 4
                for (int d = 0; d < 16; ++d)
                    u += dQ1[h * 16 + d] * (double)Wk1[(size_t)g * E_ + h * 16 + d];
                dUZ[idx] = u;
            }
            __syncthreads();
            // F2: scores
            for (int idx = tid; idx < 1024; idx += 512) {
                int k = idx & 127, h = idx >> 7;
                if (k < NN) {
                    bool mk;
                    if (k == 0) mk = (sMaskDepot != 0);
                    else {
                        int c = k - 1;
                        bool vis = (c < 64) ? ((sVis0 >> c) & 1ull) : ((sVis1 >> (c - 64)) & 1ull);
                        mk = vis || (sDem[c] > sD);
                    }
                    if (mk) dSc[h * NN + k] = NEGV;
                    else {
                        const float* ek = emb + (size_t)k * E_;
                        double s = 0.0;
                        for (int g = 0; g < E_; ++g)
                            s += (double)ek[g] * dUZ[g * 8 + h];
                        dSc[h * NN + k] = s;
                    }
                }
            }
            __syncthreads();
            // F3: per-head softmax (wave h), normalized weights in place
            {
                int h = tid >> 6, lane = tid & 63;
                int kA = lane, kB = lane + 64;
                double v1 = dSc[h * NN + kA];
                double v2 = (kB < NN) ? dSc[h * NN + kB] : -1.0e300;
                double m = fmax(v1, v2);
#pragma unroll
                for (int off = 32; off > 0; off >>= 1)
                    m = fmax(m, __shfl_xor(m, off));
                double e1 = exp(v1 - m);
                double e2 = (kB < NN) ? exp(v2 - m) : 0.0;
                double s = e1 + e2;
#pragma unroll
                for (int off = 32; off > 0; off >>= 1)
                    s += __shfl_xor(s, off);
                double inv = 1.0 / s;
                dSc[h * NN + kA] = e1 * inv;
                if (kB < NN) dSc[h * NN + kB] = e2 * inv;
            }
            __syncthreads();
            // F4: z[g][h] = sum_k w[h][k] emb[k][g]
            for (int idx = tid; idx < 1024; idx += 512) {
                int g = idx >> 3, h = idx & 7;
                double z = 0.0;
                for (int k = 0; k < NN; ++k)
                    z += dSc[h * NN + k] * (double)emb[(size_t)k * E_ + g];
                dUZ[idx] = z;
            }
            __syncthreads();
            // F5: glimpse
            if (tid < E_) {
                int h = tid >> 4;
                double gl = 0.0;
                for (int g = 0; g < E_; ++g)
                    gl += dUZ[g * 8 + h] * (double)Wv[(size_t)g * E_ + tid];
                dGl[tid] = gl;
            }
            __syncthreads();
            // F6: vg = M64 @ glimpse
            if (tid < E_) {
                double v = 0.0;
                for (int e = 0; e < E_; ++e)
                    v += dGl[e] * M64[(size_t)tid * E_ + e];
                dVg[tid] = v;
            }
            __syncthreads();
            // F7: xd[k] (reuse dQ1)
            if (tid < NN) {
                const float* ek = emb + (size_t)tid * E_;
                double x = 0.0;
                for (int g = 0; g < E_; ++g)
                    x += (double)ek[g] * dVg[g];
                dQ1[tid] = x * INVSQED;
            }
            __syncthreads();
            // F8: fp64 argmax + LSE + commit
            if (tid < 64) {
                int kA = tid, kB = tid + 64;
                double x1 = dQ1[kA];
                bool mk1;
                if (kA == 0) mk1 = (sMaskDepot != 0);
                else {
                    int c = kA - 1;
                    bool vis = (c < 64) ? ((sVis0 >> c) & 1ull) : ((sVis1 >> (c - 64)) & 1ull);
                    mk1 = vis || (sDem[c] > sD);
                }
                double x2 = 0.0; bool mk2 = true;
                if (kB < NN) {
                    x2 = dQ1[kB];
                    int c = kB - 1;
                    bool vis = (c < 64) ? ((sVis0 >> c) & 1ull) : ((sVis1 >> (c - 64)) & 1ull);
                    mk2 = vis || (sDem[c] > sD);
                }
                double a1 = mk1 ? -1.0e300 : x1;
                double a2 = (kB < NN && !mk2) ? x2 : -1.0e300;
                double mv; int mi;
                if (a1 >= a2) { mv = a1; mi = kA; } else { mv = a2; mi = kB; }
#pragma unroll
                for (int off = 32; off > 0; off >>= 1) {
                    double ov = __shfl_xor(mv, off);
                    int    oi = __shfl_xor(mi, off);
                    if (ov > mv || (ov == mv && oi < mi)) { mv = ov; mi = oi; }
                }
                double lmax = 10.0 * tanh(mv);
                double l1 = mk1 ? NEGV : 10.0 * tanh(x1);
                double l2 = (kB < NN) ? (mk2 ? NEGV : 10.0 * tanh(x2)) : 0.0;
                double s = exp(l1 - lmax) + ((kB < NN) ? exp(l2 - lmax) : 0.0);
#pragma unroll
                for (int off = 32; off > 0; off >>= 1)
                    s += __shfl_xor(s, off);
                if (tid == 0) {
                    int nxt = mi;
                    sLL += -log(s);
                    bool isdep = (nxt == 0);
                    if (isdep) {
                        sD = 1.0f;
                    } else {
                        int c = nxt - 1;
                        sD = sD - sDem[c];
                        if (c < 64) sVis0 |= (1ull << c);
                        else        sVis1 |= (1ull << (c - 64));
                    }
                    bool allv = (sVis0 == 0xFFFFFFFFFFFFFFFFull) &&
                                (sVis1 == 0x0000000FFFFFFFFFull);
                    sMaskDepot = (isdep && !allv) ? 1 : 0;
                    sPrev = nxt;
                    float cx = sCoord[2 * nxt], cy = sCoord[2 * nxt + 1];
                    double dx = (double)cx - (double)sPosX;
                    double dy = (double)cy - (double)sPosY;
                    sCost += sqrt(dx * dx + dy * dy + 1e-10);
                    sPosX = cx; sPosY = cy;
                    sTrig = 0;
                }
            }
            __syncthreads();
        }
    }

    if (tid == 0) {
        double dx = (double)sCoord[0] - (double)sPosX;
        double dy = (double)sCoord[1] - (double)sPosY;
        out[b]      = (float)(sCost + sqrt(dx * dx + dy * dy + 1e-10));
        out[B_ + b] = (float)sLL;
    }
}

// ---------------------------------------------------------------------------
extern "C" void kernel_launch(void* const* d_in, const int* in_sizes, int n_in,
                              void* d_out, int out_size, void* d_ws, size_t ws_size,
                              hipStream_t stream) {
    const float* depot = (const float*)d_in[0];
    const float* cust  = (const float*)d_in[1];
    const float* dem   = (const float*)d_in[2];
    const float* nemb  = (const float*)d_in[3];
    const float* gemb  = (const float*)d_in[4];
    const float* Wk1   = (const float*)d_in[5];
    const float* Wv    = (const float*)d_in[6];
    const float* Wk2   = (const float*)d_in[7];
    const float* Wqf   = (const float*)d_in[8];
    const float* Wout  = (const float*)d_in[9];
    const float* Wqs   = (const float*)d_in[10];
    float*  out = (float*)d_out;
    double* M64 = (double*)d_ws;                       // 128 KB
    float*  M32 = (float*)((char*)d_ws + 131072);      // 64 KB

    k_weights<<<dim3(128), dim3(128), 0, stream>>>(Wk2, Wout, M64, M32);
    k_decode <<<dim3(B_),  dim3(512), 0, stream>>>(depot, cust, dem, nemb, gemb,
                                                   Wk1, Wv, Wqf, Wqs, M64, M32, out);
}

// Round 4
// 9366.413 us; speedup vs baseline: 1.1475x; 1.1475x over previous
//
#include <hip/hip_runtime.h>
#include <math.h>

// Problem constants (match reference)
#define B_   1024
#define NC   100
#define NN   101          // N = NC + 1
#define E_   128
#define T_   202          // 2*N
#define NEGV   -1.0e9
#define GAPTHR 4.0e-3f    // fp32-path error bound ~3e-4 -> 13x margin
#define INVSQE 0.08838834764831845f
#define INVSQED 0.08838834764831845

// ---------------------------------------------------------------------------
// kernel 0: M = Wk2 @ Wout^T (128x128) into ws as fp64 (fallback) + fp32 (fast)
// ---------------------------------------------------------------------------
__global__ void k_weights(const float* __restrict__ Wk2,
                          const float* __restrict__ Wout,
                          double* __restrict__ M64,
                          float* __restrict__ M32) {
    int g = blockIdx.x;   // 0..127
    int e = threadIdx.x;  // 0..127
    const float* w2 = Wk2 + g * E_;
    const float* wo = Wout + e * E_;
    double acc = 0.0;
#pragma unroll 8
    for (int f = 0; f < E_; ++f) acc += (double)w2[f] * (double)wo[f];
    M64[g * E_ + e] = acc;
    M32[g * E_ + e] = (float)acc;
}

// ---------------------------------------------------------------------------
// Main decoder. 1 block / batch element, 512 threads (8 waves), 2 blocks/CU.
// Register state: rK1[32] + rK2[32] only (=64) -> no spill at 128-reg cap.
// LDS: V[101][128] fp32 + union scratch (~74 KB total).
// Kstep rows in global ws (gks); q1 folded inline into phase B (4 barriers).
// Exact fp64 fallback when top-2 pre-tanh logit gap < GAPTHR (rare).
// ---------------------------------------------------------------------------
__global__ __launch_bounds__(512, 4)
void k_decode(const float* __restrict__ depot_xy,
              const float* __restrict__ customer_xy,
              const float* __restrict__ demand,
              const float* __restrict__ node_emb,
              const float* __restrict__ graph_emb,
              const float* __restrict__ Wk1,
              const float* __restrict__ Wv,
              const float* __restrict__ Wq_fixed,
              const float* __restrict__ Wq_step,
              const double* __restrict__ M64,
              const float* __restrict__ M32,
              float* __restrict__ gks,          // [B][101][128] Kstep, or null
              float* __restrict__ out)          // [2*B]: cost then ll
{
    __shared__ float  sV[NN * E_];              // 51.7 KB, V rows fp32
    __shared__ double sU[2224];                 // union scratch 17.8 KB
    __shared__ double sQfix64[E_];
    __shared__ double sWqD64[E_];
    __shared__ float  sQfix32[E_];
    __shared__ float  sWqD32[E_];
    __shared__ float  sCoord[2 * NN];
    __shared__ float  sDem[NC];
    __shared__ float  sD;
    __shared__ double sCost, sLL;
    __shared__ float  sPosX, sPosY;
    __shared__ int    sPrev, sMaskDepot, sTrig, sOvf;
    __shared__ unsigned long long sVis0, sVis1;

    // fast fp32 views
    float* fQ1   = (float*)sU;          // [128]   (only used when !gks)
    float* fSc   = (float*)sU + 128;    // [8][104] exp-scores (pads 101..103)
    float* fPart = (float*)sU + 960;    // [4][128] glimpse partials
    float* fPx   = (float*)sU + 1472;   // [4][128] logit partials
    float* fPs   = (float*)sU + 1984;   // [4][8]   per-(chunk,head) exp sums
    // fallback fp64 views
    double* dUZ = sU;                   // [128][8] u1 then z
    double* dSc = sU + 1024;            // [8][101] scores -> weights
    double* dQ1 = sU + 1832;            // [128] q1, later xd[101]
    double* dGl = sU + 1960;            // [128]
    double* dVg = sU + 2088;            // [128]

    const int b      = blockIdx.x;
    const int tid    = threadIdx.x;
    const int k_lane = tid & 127;
    const int q2u    = __builtin_amdgcn_readfirstlane(tid >> 7);  // 0..3
    const int e0     = q2u * 32;
    const int kb     = q2u * 26;

    const float* emb = node_emb + (size_t)b * NN * E_;

    // ---------------- prologue ----------------
    if (tid < E_) {
        const float* ge = graph_emb + (size_t)b * E_;
        double acc = 0.0;
        for (int g = 0; g < E_; ++g)
            acc += (double)ge[g] * (double)Wq_fixed[g * E_ + tid];
        sQfix64[tid] = acc;
        sQfix32[tid] = (float)acc;
        sWqD64[tid]  = (double)Wq_step[128 * E_ + tid];
        sWqD32[tid]  = Wq_step[128 * E_ + tid];
    }
    if (tid < 2 * NN) {
        int k = tid >> 1, xy = tid & 1;
        sCoord[tid] = (k == 0) ? depot_xy[(size_t)b * 2 + xy]
                               : customer_xy[((size_t)b * NC + (k - 1)) * 2 + xy];
    }
    if (tid < NC) sDem[tid] = demand[(size_t)b * NC + tid];
    if (tid == 0) {
        sD = 1.f; sPrev = 0; sVis0 = 0ull; sVis1 = 0ull;
        sMaskDepot = 1; sCost = 0.0; sLL = 0.0; sTrig = 0; sOvf = 0;
        sPosX = depot_xy[(size_t)b * 2 + 0];
        sPosY = depot_xy[(size_t)b * 2 + 1];
    }

    // V into LDS fp32; Kstep into gks (global) if available
    for (int idx = tid; idx < NN * 32; idx += 512) {
        int k  = idx >> 5;
        int e4 = (idx & 31) * 4;
        const float* er = emb + (size_t)k * E_;
        float4 aV = {0.f, 0.f, 0.f, 0.f};
        float4 aK = {0.f, 0.f, 0.f, 0.f};
        for (int g = 0; g < E_; ++g) {
            float eg = er[g];
            float4 wv = *(const float4*)(Wv + (size_t)g * E_ + e4);
            aV.x += eg * wv.x; aV.y += eg * wv.y;
            aV.z += eg * wv.z; aV.w += eg * wv.w;
            if (gks) {
                float4 wq = *(const float4*)(Wq_step + (size_t)g * E_ + e4);
                aK.x += eg * wq.x; aK.y += eg * wq.y;
                aK.z += eg * wq.z; aK.w += eg * wq.w;
            }
        }
        *(float4*)(sV + (size_t)k * E_ + e4) = aV;
        if (gks)
            *(float4*)(gks + ((size_t)b * NN + k) * E_ + e4) = aK;
    }

    // K1, K2t chunks (32 cols) into registers (fp32)
    float rK1[32], rK2[32];
#pragma unroll
    for (int j = 0; j < 32; ++j) { rK1[j] = 0.f; rK2[j] = 0.f; }
    if (k_lane < NN) {
        const float* er = emb + (size_t)k_lane * E_;
        for (int g = 0; g < E_; ++g) {
            float eg = er[g];
            const float* w1 = Wk1 + (size_t)g * E_ + e0;
            const float* mm = M32 + (size_t)g * E_ + e0;
#pragma unroll
            for (int j = 0; j < 32; ++j) {
                rK1[j] += eg * w1[j];
                rK2[j] += eg * mm[j];
            }
        }
    }
    __syncthreads();

    // ---------------- sequential decode loop ----------------
    for (int t = 0; t < T_; ++t) {
        // ---- A (only when no gks): q1 into LDS ----
        if (!gks) {
            if (tid < E_) {
                const float* ep = emb + (size_t)sPrev * E_;
                float ks = 0.f;
                for (int g = 0; g < E_; ++g)
                    ks += ep[g] * Wq_step[(size_t)g * E_ + tid];
                fQ1[tid] = (sQfix32[tid] + ks + sD * sWqD32[tid]) * 0.25f;
            }
            __syncthreads();
        }

        // ---- B: exp-scores (q1 inline from gks row; masked -> 0) ----
        if (k_lane < 104) {
            bool mk;
            if (k_lane == 0)       mk = (sMaskDepot != 0);
            else if (k_lane >= NN) mk = true;
            else {
                int c = k_lane - 1;
                bool vis = (c < 64) ? ((sVis0 >> c) & 1ull)
                                    : ((sVis1 >> (c - 64)) & 1ull);
                mk = vis || (sDem[c] > sD);
            }
            int h0 = 2 * q2u;
            if (mk) {
                fSc[h0 * 104 + k_lane]       = 0.f;
                fSc[(h0 + 1) * 104 + k_lane] = 0.f;
            } else {
                float s0 = 0.f, s1 = 0.f;
                if (gks) {
                    const float* gr = gks + ((size_t)b * NN + sPrev) * E_ + e0;
                    float Dv = sD;
#pragma unroll
                    for (int j = 0; j < 16; ++j) {
                        float q = (sQfix32[e0 + j] + gr[j] + Dv * sWqD32[e0 + j]) * 0.25f;
                        s0 += rK1[j] * q;
                    }
#pragma unroll
                    for (int j = 16; j < 32; ++j) {
                        float q = (sQfix32[e0 + j] + gr[j] + Dv * sWqD32[e0 + j]) * 0.25f;
                        s1 += rK1[j] * q;
                    }
                } else {
#pragma unroll
                    for (int j = 0; j < 16; ++j) s0 += rK1[j]      * fQ1[e0 + j];
#pragma unroll
                    for (int j = 16; j < 32; ++j) s1 += rK1[j]     * fQ1[e0 + j];
                }
                if (s0 > 80.f || s1 > 80.f) { sOvf = 1; s0 = fminf(s0, 80.f); s1 = fminf(s1, 80.f); }
                fSc[h0 * 104 + k_lane]       = expf(s0);
                fSc[(h0 + 1) * 104 + k_lane] = expf(s1);
            }
        }
        __syncthreads();

        // ---- C: glimpse partials + per-(chunk,head) exp sums ----
        {
            int e = k_lane, h = e >> 4;
            float p = 0.f, ssum = 0.f;
#pragma unroll
            for (int j = 0; j < 26; ++j) {
                float w = fSc[h * 104 + kb + j];   // pads are 0
                p    += w * sV[(size_t)(kb + j) * E_ + e];
                ssum += w;
            }
            fPart[q2u * E_ + e] = p;
            if ((e & 15) == 0) fPs[q2u * 8 + h] = ssum;
        }
        __syncthreads();

        // ---- D: logit partials (normalization folded in) ----
        if (k_lane < NN) {
            int h0 = 2 * q2u;
            float sA = fPs[h0] + fPs[8 + h0] + fPs[16 + h0] + fPs[24 + h0];
            float sB = fPs[h0 + 1] + fPs[8 + h0 + 1] + fPs[16 + h0 + 1] + fPs[24 + h0 + 1];
            float invA = 1.f / sA, invB = 1.f / sB;
            float xa = 0.f, xb = 0.f;
#pragma unroll
            for (int j = 0; j < 16; ++j) {
                int e = e0 + j;
                float gl = fPart[e] + fPart[128 + e] + fPart[256 + e] + fPart[384 + e];
                xa += rK2[j] * gl;
            }
#pragma unroll
            for (int j = 16; j < 32; ++j) {
                int e = e0 + j;
                float gl = fPart[e] + fPart[128 + e] + fPart[256 + e] + fPart[384 + e];
                xb += rK2[j] * gl;
            }
            fPx[q2u * E_ + k_lane] = xa * invA + xb * invB;
        }
        __syncthreads();

        // ---- E: top-2 argmax (pre-tanh), gap test, commit-or-trigger ----
        if (tid < 64) {
            int kA = tid, kB = tid + 64;
            float xA = (fPx[kA] + fPx[128 + kA] + fPx[256 + kA] + fPx[384 + kA]) * INVSQE;
            bool mk1;
            if (kA == 0) mk1 = (sMaskDepot != 0);
            else {
                int c = kA - 1;
                bool vis = (c < 64) ? ((sVis0 >> c) & 1ull) : ((sVis1 >> (c - 64)) & 1ull);
                mk1 = vis || (sDem[c] > sD);
            }
            float xB = -3.0e38f; bool mk2 = true;
            if (kB < NN) {
                xB = (fPx[kB] + fPx[128 + kB] + fPx[256 + kB] + fPx[384 + kB]) * INVSQE;
                int c = kB - 1;
                bool vis = (c < 64) ? ((sVis0 >> c) & 1ull) : ((sVis1 >> (c - 64)) & 1ull);
                mk2 = vis || (sDem[c] > sD);
            }
            float a1v = mk1 ? -3.0e38f : xA;
            float a2v = mk2 ? -3.0e38f : xB;
            float m1, m2; int mi;
            if (a2v > a1v) { m1 = a2v; m2 = a1v; mi = kB; }
            else           { m1 = a1v; m2 = a2v; mi = kA; }
            float ls = 0.f;
            if (!mk1)              ls += expf(10.f * tanhf(xA));
            if (kB < NN && !mk2)   ls += expf(10.f * tanhf(xB));
#pragma unroll
            for (int off = 32; off > 0; off >>= 1) {
                float om1 = __shfl_xor(m1, off);
                float om2 = __shfl_xor(m2, off);
                float os  = __shfl_xor(ls, off);
                int   omi = __shfl_xor(mi, off);
                ls += os;
                if (om1 > m1 || (om1 == m1 && omi < mi)) {
                    m2 = fmaxf(m1, om2); m1 = om1; mi = omi;
                } else {
                    m2 = fmaxf(m2, om1);
                }
            }
            if (tid == 0) {
                float gap = m1 - m2;
                bool trig = !(gap >= GAPTHR) || (sOvf != 0);   // NaN-safe
                sOvf = 0;
                if (trig) {
                    sTrig = 1;
                } else {
                    float lsel = 10.f * tanhf(m1);
                    float logp = lsel - logf(ls);
                    int nxt = mi;
                    sLL += (double)logp;
                    bool isdep = (nxt == 0);
                    if (isdep) {
                        sD = 1.0f;
                    } else {
                        int c = nxt - 1;
                        sD = sD - sDem[c];
                        if (c < 64) sVis0 |= (1ull << c);
                        else        sVis1 |= (1ull << (c - 64));
                    }
                    bool allv = (sVis0 == 0xFFFFFFFFFFFFFFFFull) &&
                                (sVis1 == 0x0000000FFFFFFFFFull);
                    sMaskDepot = (isdep && !allv) ? 1 : 0;
                    sPrev = nxt;
                    float cx = sCoord[2 * nxt], cy = sCoord[2 * nxt + 1];
                    double dx = (double)cx - (double)sPosX;
                    double dy = (double)cy - (double)sPosY;
                    sCost += sqrt(dx * dx + dy * dy + 1e-10);
                    sPosX = cx; sPosY = cy;
                }
            }
        }
        __syncthreads();

        // ---- Fallback: exact fp64 recompute of this step (rare) ----
        if (sTrig) {
            // F0: q1d
            if (tid < E_) {
                const float* ep = emb + (size_t)sPrev * E_;
                double ks = 0.0;
                for (int g = 0; g < E_; ++g)
                    ks += (double)ep[g] * (double)Wq_step[(size_t)g * E_ + tid];
                dQ1[tid] = (sQfix64[tid] + ks + (double)sD * sWqD64[tid]) * 0.25;
            }
            __syncthreads();
            // F1: u1[g][h]
            for (int idx = tid; idx < 1024; idx += 512) {
                int g = idx >> 3, h = idx & 7;
                double u = 0.0;
#pragma unroll 4
                for (int d = 0; d < 16; ++d)
                    u += dQ1[h * 16 + d] * (double)Wk1[(size_t)g * E_ + h * 16 + d];
                dUZ[idx] = u;
            }
            __syncthreads();
            // F2: scores
            for (int idx = tid; idx < 1024; idx += 512) {
                int k = idx & 127, h = idx >> 7;
                if (k < NN) {
                    bool mk;
                    if (k == 0) mk = (sMaskDepot != 0);
                    else {
                        int c = k - 1;
                        bool vis = (c < 64) ? ((sVis0 >> c) & 1ull) : ((sVis1 >> (c - 64)) & 1ull);
                        mk = vis || (sDem[c] > sD);
                    }
                    if (mk) dSc[h * NN + k] = NEGV;
                    else {
                        const float* ek = emb + (size_t)k * E_;
                        double s = 0.0;
                        for (int g = 0; g < E_; ++g)
                            s += (double)ek[g] * dUZ[g * 8 + h];
                        dSc[h * NN + k] = s;
                    }
                }
            }
            __syncthreads();
            // F3: per-head softmax (wave h), normalized weights in place
            {
                int h = tid >> 6, lane = tid & 63;
                int kA = lane, kB = lane + 64;
                double v1 = dSc[h * NN + kA];
                double v2 = (kB < NN) ? dSc[h * NN + kB] : -1.0e300;
                double m = fmax(v1, v2);
#pragma unroll
                for (int off = 32; off > 0; off >>= 1)
                    m = fmax(m, __shfl_xor(m, off));
                double e1 = exp(v1 - m);
                double e2 = (kB < NN) ? exp(v2 - m) : 0.0;
                double s = e1 + e2;
#pragma unroll
                for (int off = 32; off > 0; off >>= 1)
                    s += __shfl_xor(s, off);
                double inv = 1.0 / s;
                dSc[h * NN + kA] = e1 * inv;
                if (kB < NN) dSc[h * NN + kB] = e2 * inv;
            }
            __syncthreads();
            // F4: z[g][h] = sum_k w[h][k] emb[k][g]
            for (int idx = tid; idx < 1024; idx += 512) {
                int g = idx >> 3, h = idx & 7;
                double z = 0.0;
                for (int k = 0; k < NN; ++k)
                    z += dSc[h * NN + k] * (double)emb[(size_t)k * E_ + g];
                dUZ[idx] = z;
            }
            __syncthreads();
            // F5: glimpse
            if (tid < E_) {
                int h = tid >> 4;
                double gl = 0.0;
                for (int g = 0; g < E_; ++g)
                    gl += dUZ[g * 8 + h] * (double)Wv[(size_t)g * E_ + tid];
                dGl[tid] = gl;
            }
            __syncthreads();
            // F6: vg = M64 @ glimpse
            if (tid < E_) {
                double v = 0.0;
                for (int e = 0; e < E_; ++e)
                    v += dGl[e] * M64[(size_t)tid * E_ + e];
                dVg[tid] = v;
            }
            __syncthreads();
            // F7: xd[k] (reuse dQ1)
            if (tid < NN) {
                const float* ek = emb + (size_t)tid * E_;
                double x = 0.0;
                for (int g = 0; g < E_; ++g)
                    x += (double)ek[g] * dVg[g];
                dQ1[tid] = x * INVSQED;
            }
            __syncthreads();
            // F8: fp64 argmax + LSE + commit
            if (tid < 64) {
                int kA = tid, kB = tid + 64;
                double x1 = dQ1[kA];
                bool mk1;
                if (kA == 0) mk1 = (sMaskDepot != 0);
                else {
                    int c = kA - 1;
                    bool vis = (c < 64) ? ((sVis0 >> c) & 1ull) : ((sVis1 >> (c - 64)) & 1ull);
                    mk1 = vis || (sDem[c] > sD);
                }
                double x2 = 0.0; bool mk2 = true;
                if (kB < NN) {
                    x2 = dQ1[kB];
                    int c = kB - 1;
                    bool vis = (c < 64) ? ((sVis0 >> c) & 1ull) : ((sVis1 >> (c - 64)) & 1ull);
                    mk2 = vis || (sDem[c] > sD);
                }
                double a1 = mk1 ? -1.0e300 : x1;
                double a2 = (kB < NN && !mk2) ? x2 : -1.0e300;
                double mv; int mi;
                if (a1 >= a2) { mv = a1; mi = kA; } else { mv = a2; mi = kB; }
#pragma unroll
                for (int off = 32; off > 0; off >>= 1) {
                    double ov = __shfl_xor(mv, off);
                    int    oi = __shfl_xor(mi, off);
                    if (ov > mv || (ov == mv && oi < mi)) { mv = ov; mi = oi; }
                }
                double lmax = 10.0 * tanh(mv);
                double l1 = mk1 ? NEGV : 10.0 * tanh(x1);
                double l2 = (kB < NN) ? (mk2 ? NEGV : 10.0 * tanh(x2)) : 0.0;
                double s = exp(l1 - lmax) + ((kB < NN) ? exp(l2 - lmax) : 0.0);
#pragma unroll
                for (int off = 32; off > 0; off >>= 1)
                    s += __shfl_xor(s, off);
                if (tid == 0) {
                    int nxt = mi;
                    sLL += -log(s);
                    bool isdep = (nxt == 0);
                    if (isdep) {
                        sD = 1.0f;
                    } else {
                        int c = nxt - 1;
                        sD = sD - sDem[c];
                        if (c < 64) sVis0 |= (1ull << c);
                        else        sVis1 |= (1ull << (c - 64));
                    }
                    bool allv = (sVis0 == 0xFFFFFFFFFFFFFFFFull) &&
                                (sVis1 == 0x0000000FFFFFFFFFull);
                    sMaskDepot = (isdep && !allv) ? 1 : 0;
                    sPrev = nxt;
                    float cx = sCoord[2 * nxt], cy = sCoord[2 * nxt + 1];
                    double dx = (double)cx - (double)sPosX;
                    double dy = (double)cy - (double)sPosY;
                    sCost += sqrt(dx * dx + dy * dy + 1e-10);
                    sPosX = cx; sPosY = cy;
                    sTrig = 0;
                }
            }
            __syncthreads();
        }
    }

    if (tid == 0) {
        double dx = (double)sCoord[0] - (double)sPosX;
        double dy = (double)sCoord[1] - (double)sPosY;
        out[b]      = (float)(sCost + sqrt(dx * dx + dy * dy + 1e-10));
        out[B_ + b] = (float)sLL;
    }
}

// ---------------------------------------------------------------------------
extern "C" void kernel_launch(void* const* d_in, const int* in_sizes, int n_in,
                              void* d_out, int out_size, void* d_ws, size_t ws_size,
                              hipStream_t stream) {
    const float* depot = (const float*)d_in[0];
    const float* cust  = (const float*)d_in[1];
    const float* dem   = (const float*)d_in[2];
    const float* nemb  = (const float*)d_in[3];
    const float* gemb  = (const float*)d_in[4];
    const float* Wk1   = (const float*)d_in[5];
    const float* Wv    = (const float*)d_in[6];
    const float* Wk2   = (const float*)d_in[7];
    const float* Wqf   = (const float*)d_in[8];
    const float* Wout  = (const float*)d_in[9];
    const float* Wqs   = (const float*)d_in[10];
    float*  out = (float*)d_out;
    double* M64 = (double*)d_ws;                       // 128 KB
    float*  M32 = (float*)((char*)d_ws + 131072);      // 64 KB

    // Kstep workspace: [B][101][128] fp32 = 52.95 MB, if ws is big enough
    const size_t gks_off    = 196608;
    const size_t gks_bytes  = (size_t)B_ * NN * E_ * sizeof(float);
    float* gks = (ws_size >= gks_off + gks_bytes)
               ? (float*)((char*)d_ws + gks_off) : nullptr;

    k_weights<<<dim3(128), dim3(128), 0, stream>>>(Wk2, Wout, M64, M32);
    k_decode <<<dim3(B_),  dim3(512), 0, stream>>>(depot, cust, dem, nemb, gemb,
                                                   Wk1, Wv, Wqf, Wqs, M64, M32,
                                                   gks, out);
}

// Round 5
// 6207.376 us; speedup vs baseline: 1.7315x; 1.5089x over previous
//
#include <hip/hip_runtime.h>
#include <math.h>

// Problem constants (match reference)
#define B_   1024
#define NC   100
#define NN   101          // N = NC + 1
#define E_   128
#define T_   202          // 2*N
#define NEGV   -1.0e9
#define GAPTHR 4.0e-3f    // fp32-path error bound ~3e-4 -> 13x margin
#define INVSQE 0.08838834764831845f
#define INVSQED 0.08838834764831845

// ---------------------------------------------------------------------------
// kernel 0: M = Wk2 @ Wout^T (128x128) into ws as fp64 (fallback) + fp32 (fast)
// ---------------------------------------------------------------------------
__global__ void k_weights(const float* __restrict__ Wk2,
                          const float* __restrict__ Wout,
                          double* __restrict__ M64,
                          float* __restrict__ M32) {
    int g = blockIdx.x;   // 0..127
    int e = threadIdx.x;  // 0..127
    const float* w2 = Wk2 + g * E_;
    const float* wo = Wout + e * E_;
    double acc = 0.0;
#pragma unroll 8
    for (int f = 0; f < E_; ++f) acc += (double)w2[f] * (double)wo[f];
    M64[g * E_ + e] = acc;
    M32[g * E_ + e] = (float)acc;
}

// ---------------------------------------------------------------------------
// Main decoder. 1 block / batch element, 512 threads (8 waves), 1 block/CU.
// __launch_bounds__(512,2): unified reg cap 256/wave -> rK1/rK2 stay in
// registers (round-4's (512,4) cap of 128 spilled them to scratch: 16.5 GB
// of HBM traffic). LDS: V + Kstep + union scratch ~123 KB.
// Fast path fp32, 4 barriers/step; exact fp64 fallback on near-tie argmax.
// ---------------------------------------------------------------------------
__global__ __launch_bounds__(512, 2)
void k_decode(const float* __restrict__ depot_xy,
              const float* __restrict__ customer_xy,
              const float* __restrict__ demand,
              const float* __restrict__ node_emb,
              const float* __restrict__ graph_emb,
              const float* __restrict__ Wk1,
              const float* __restrict__ Wv,
              const float* __restrict__ Wq_fixed,
              const float* __restrict__ Wq_step,
              const double* __restrict__ M64,
              const float* __restrict__ M32,
              float* __restrict__ out)          // [2*B]: cost then ll
{
    __shared__ float  sV [NN * E_];             // 51.7 KB, V rows fp32
    __shared__ float  sKs[NN * E_];             // 51.7 KB, Kstep rows fp32
    __shared__ double sU[2224];                 // union scratch 17.8 KB
    __shared__ double sQfix64[E_];
    __shared__ double sWqD64[E_];
    __shared__ float  sQfix32[E_];
    __shared__ float  sWqD32[E_];
    __shared__ float  sCoord[2 * NN];
    __shared__ float  sDem[NC];
    __shared__ float  sD;
    __shared__ double sCost, sLL;
    __shared__ float  sPosX, sPosY;
    __shared__ int    sPrev, sMaskDepot, sTrig, sOvf;
    __shared__ unsigned long long sVis0, sVis1;

    // fast fp32 views
    float* fSc   = (float*)sU + 128;    // [8][104] exp-scores (pads 101..103)
    float* fPart = (float*)sU + 960;    // [4][128] glimpse partials
    float* fPx   = (float*)sU + 1472;   // [4][128] logit partials
    float* fPs   = (float*)sU + 1984;   // [4][8]   per-(chunk,head) exp sums
    // fallback fp64 views
    double* dUZ = sU;                   // [128][8] u1 then z
    double* dSc = sU + 1024;            // [8][101] scores -> weights
    double* dQ1 = sU + 1832;            // [128] q1, later xd[101]
    double* dGl = sU + 1960;            // [128]
    double* dVg = sU + 2088;            // [128]

    const int b      = blockIdx.x;
    const int tid    = threadIdx.x;
    const int k_lane = tid & 127;
    const int q2u    = __builtin_amdgcn_readfirstlane(tid >> 7);  // 0..3
    const int e0     = q2u * 32;
    const int kb     = q2u * 26;

    const float* emb = node_emb + (size_t)b * NN * E_;

    // ---------------- prologue ----------------
    if (tid < E_) {
        const float* ge = graph_emb + (size_t)b * E_;
        double acc = 0.0;
        for (int g = 0; g < E_; ++g)
            acc += (double)ge[g] * (double)Wq_fixed[g * E_ + tid];
        sQfix64[tid] = acc;
        sQfix32[tid] = (float)acc;
        sWqD64[tid]  = (double)Wq_step[128 * E_ + tid];
        sWqD32[tid]  = Wq_step[128 * E_ + tid];
    }
    if (tid < 2 * NN) {
        int k = tid >> 1, xy = tid & 1;
        sCoord[tid] = (k == 0) ? depot_xy[(size_t)b * 2 + xy]
                               : customer_xy[((size_t)b * NC + (k - 1)) * 2 + xy];
    }
    if (tid < NC) sDem[tid] = demand[(size_t)b * NC + tid];
    if (tid == 0) {
        sD = 1.f; sPrev = 0; sVis0 = 0ull; sVis1 = 0ull;
        sMaskDepot = 1; sCost = 0.0; sLL = 0.0; sTrig = 0; sOvf = 0;
        sPosX = depot_xy[(size_t)b * 2 + 0];
        sPosY = depot_xy[(size_t)b * 2 + 1];
    }

    // V and Kstep into LDS (fp32, float4 over columns)
    for (int idx = tid; idx < NN * 32; idx += 512) {
        int k  = idx >> 5;
        int e4 = (idx & 31) * 4;
        const float* er = emb + (size_t)k * E_;
        float4 aV = {0.f, 0.f, 0.f, 0.f};
        float4 aK = {0.f, 0.f, 0.f, 0.f};
        for (int g = 0; g < E_; ++g) {
            float eg = er[g];
            float4 wv = *(const float4*)(Wv      + (size_t)g * E_ + e4);
            float4 wq = *(const float4*)(Wq_step + (size_t)g * E_ + e4);
            aV.x += eg * wv.x; aV.y += eg * wv.y;
            aV.z += eg * wv.z; aV.w += eg * wv.w;
            aK.x += eg * wq.x; aK.y += eg * wq.y;
            aK.z += eg * wq.z; aK.w += eg * wq.w;
        }
        *(float4*)(sV  + (size_t)k * E_ + e4) = aV;
        *(float4*)(sKs + (size_t)k * E_ + e4) = aK;
    }

    // K1, K2t chunks (32 cols) into registers (fp32)
    float rK1[32], rK2[32];
#pragma unroll
    for (int j = 0; j < 32; ++j) { rK1[j] = 0.f; rK2[j] = 0.f; }
    if (k_lane < NN) {
        const float* er = emb + (size_t)k_lane * E_;
        for (int g = 0; g < E_; ++g) {
            float eg = er[g];
            const float* w1 = Wk1 + (size_t)g * E_ + e0;
            const float* mm = M32 + (size_t)g * E_ + e0;
#pragma unroll
            for (int j = 0; j < 32; ++j) {
                rK1[j] += eg * w1[j];
                rK2[j] += eg * mm[j];
            }
        }
    }
    __syncthreads();

    // ---------------- sequential decode loop ----------------
    for (int t = 0; t < T_; ++t) {
        // ---- B: exp-scores (q1 inline from sKs row; masked -> 0) ----
        if (k_lane < 104) {
            bool mk;
            if (k_lane == 0)       mk = (sMaskDepot != 0);
            else if (k_lane >= NN) mk = true;
            else {
                int c = k_lane - 1;
                bool vis = (c < 64) ? ((sVis0 >> c) & 1ull)
                                    : ((sVis1 >> (c - 64)) & 1ull);
                mk = vis || (sDem[c] > sD);
            }
            int h0 = 2 * q2u;
            if (mk) {
                fSc[h0 * 104 + k_lane]       = 0.f;
                fSc[(h0 + 1) * 104 + k_lane] = 0.f;
            } else {
                const float* kr = sKs + (size_t)sPrev * E_ + e0;
                float Dv = sD;
                float s0 = 0.f, s1 = 0.f;
#pragma unroll
                for (int j = 0; j < 16; ++j) {
                    float q = (sQfix32[e0 + j] + kr[j] + Dv * sWqD32[e0 + j]) * 0.25f;
                    s0 += rK1[j] * q;
                }
#pragma unroll
                for (int j = 16; j < 32; ++j) {
                    float q = (sQfix32[e0 + j] + kr[j] + Dv * sWqD32[e0 + j]) * 0.25f;
                    s1 += rK1[j] * q;
                }
                if (s0 > 80.f || s1 > 80.f) { sOvf = 1; s0 = fminf(s0, 80.f); s1 = fminf(s1, 80.f); }
                fSc[h0 * 104 + k_lane]       = expf(s0);
                fSc[(h0 + 1) * 104 + k_lane] = expf(s1);
            }
        }
        __syncthreads();

        // ---- C: glimpse partials + per-(chunk,head) exp sums ----
        {
            int e = k_lane, h = e >> 4;
            float p = 0.f, ssum = 0.f;
#pragma unroll
            for (int j = 0; j < 26; ++j) {
                float w = fSc[h * 104 + kb + j];   // pads are 0
                p    += w * sV[(size_t)(kb + j) * E_ + e];
                ssum += w;
            }
            fPart[q2u * E_ + e] = p;
            if ((e & 15) == 0) fPs[q2u * 8 + h] = ssum;
        }
        __syncthreads();

        // ---- D: logit partials (normalization folded in) ----
        if (k_lane < NN) {
            int h0 = 2 * q2u;
            float sA = fPs[h0] + fPs[8 + h0] + fPs[16 + h0] + fPs[24 + h0];
            float sB = fPs[h0 + 1] + fPs[8 + h0 + 1] + fPs[16 + h0 + 1] + fPs[24 + h0 + 1];
            float invA = 1.f / sA, invB = 1.f / sB;
            float xa = 0.f, xb = 0.f;
#pragma unroll
            for (int j = 0; j < 16; ++j) {
                int e = e0 + j;
                float gl = fPart[e] + fPart[128 + e] + fPart[256 + e] + fPart[384 + e];
                xa += rK2[j] * gl;
            }
#pragma unroll
            for (int j = 16; j < 32; ++j) {
                int e = e0 + j;
                float gl = fPart[e] + fPart[128 + e] + fPart[256 + e] + fPart[384 + e];
                xb += rK2[j] * gl;
            }
            fPx[q2u * E_ + k_lane] = xa * invA + xb * invB;
        }
        __syncthreads();

        // ---- E: top-2 argmax (pre-tanh), gap test, commit-or-trigger ----
        if (tid < 64) {
            int kA = tid, kB = tid + 64;
            float xA = (fPx[kA] + fPx[128 + kA] + fPx[256 + kA] + fPx[384 + kA]) * INVSQE;
            bool mk1;
            if (kA == 0) mk1 = (sMaskDepot != 0);
            else {
                int c = kA - 1;
                bool vis = (c < 64) ? ((sVis0 >> c) & 1ull) : ((sVis1 >> (c - 64)) & 1ull);
                mk1 = vis || (sDem[c] > sD);
            }
            float xB = -3.0e38f; bool mk2 = true;
            if (kB < NN) {
                xB = (fPx[kB] + fPx[128 + kB] + fPx[256 + kB] + fPx[384 + kB]) * INVSQE;
                int c = kB - 1;
                bool vis = (c < 64) ? ((sVis0 >> c) & 1ull) : ((sVis1 >> (c - 64)) & 1ull);
                mk2 = vis || (sDem[c] > sD);
            }
            float a1v = mk1 ? -3.0e38f : xA;
            float a2v = mk2 ? -3.0e38f : xB;
            float m1, m2; int mi;
            if (a2v > a1v) { m1 = a2v; m2 = a1v; mi = kB; }
            else           { m1 = a1v; m2 = a2v; mi = kA; }
            float ls = 0.f;
            if (!mk1)              ls += expf(10.f * tanhf(xA));
            if (kB < NN && !mk2)   ls += expf(10.f * tanhf(xB));
#pragma unroll
            for (int off = 32; off > 0; off >>= 1) {
                float om1 = __shfl_xor(m1, off);
                float om2 = __shfl_xor(m2, off);
                float os  = __shfl_xor(ls, off);
                int   omi = __shfl_xor(mi, off);
                ls += os;
                if (om1 > m1 || (om1 == m1 && omi < mi)) {
                    m2 = fmaxf(m1, om2); m1 = om1; mi = omi;
                } else {
                    m2 = fmaxf(m2, om1);
                }
            }
            if (tid == 0) {
                float gap = m1 - m2;
                bool trig = !(gap >= GAPTHR) || (sOvf != 0);   // NaN-safe
                sOvf = 0;
                if (trig) {
                    sTrig = 1;
                } else {
                    float lsel = 10.f * tanhf(m1);
                    float logp = lsel - logf(ls);
                    int nxt = mi;
                    sLL += (double)logp;
                    bool isdep = (nxt == 0);
                    if (isdep) {
                        sD = 1.0f;
                    } else {
                        int c = nxt - 1;
                        sD = sD - sDem[c];
                        if (c < 64) sVis0 |= (1ull << c);
                        else        sVis1 |= (1ull << (c - 64));
                    }
                    bool allv = (sVis0 == 0xFFFFFFFFFFFFFFFFull) &&
                                (sVis1 == 0x0000000FFFFFFFFFull);
                    sMaskDepot = (isdep && !allv) ? 1 : 0;
                    sPrev = nxt;
                    float cx = sCoord[2 * nxt], cy = sCoord[2 * nxt + 1];
                    double dx = (double)cx - (double)sPosX;
                    double dy = (double)cy - (double)sPosY;
                    sCost += sqrt(dx * dx + dy * dy + 1e-10);
                    sPosX = cx; sPosY = cy;
                }
            }
        }
        __syncthreads();

        // ---- Fallback: exact fp64 recompute of this step (rare) ----
        if (sTrig) {
            // F0: q1d
            if (tid < E_) {
                const float* ep = emb + (size_t)sPrev * E_;
                double ks = 0.0;
                for (int g = 0; g < E_; ++g)
                    ks += (double)ep[g] * (double)Wq_step[(size_t)g * E_ + tid];
                dQ1[tid] = (sQfix64[tid] + ks + (double)sD * sWqD64[tid]) * 0.25;
            }
            __syncthreads();
            // F1: u1[g][h]
            for (int idx = tid; idx < 1024; idx += 512) {
                int g = idx >> 3, h = idx & 7;
                double u = 0.0;
#pragma unroll 4
                for (int d = 0; d < 16; ++d)
                    u += dQ1[h * 16 + d] * (double)Wk1[(size_t)g * E_ + h * 16 + d];
                dUZ[idx] = u;
            }
            __syncthreads();
            // F2: scores
            for (int idx = tid; idx < 1024; idx += 512) {
                int k = idx & 127, h = idx >> 7;
                if (k < NN) {
                    bool mk;
                    if (k == 0) mk = (sMaskDepot != 0);
                    else {
                        int c = k - 1;
                        bool vis = (c < 64) ? ((sVis0 >> c) & 1ull) : ((sVis1 >> (c - 64)) & 1ull);
                        mk = vis || (sDem[c] > sD);
                    }
                    if (mk) dSc[h * NN + k] = NEGV;
                    else {
                        const float* ek = emb + (size_t)k * E_;
                        double s = 0.0;
                        for (int g = 0; g < E_; ++g)
                            s += (double)ek[g] * dUZ[g * 8 + h];
                        dSc[h * NN + k] = s;
                    }
                }
            }
            __syncthreads();
            // F3: per-head softmax (wave h), normalized weights in place
            {
                int h = tid >> 6, lane = tid & 63;
                int kA = lane, kB = lane + 64;
                double v1 = dSc[h * NN + kA];
                double v2 = (kB < NN) ? dSc[h * NN + kB] : -1.0e300;
                double m = fmax(v1, v2);
#pragma unroll
                for (int off = 32; off > 0; off >>= 1)
                    m = fmax(m, __shfl_xor(m, off));
                double e1 = exp(v1 - m);
                double e2 = (kB < NN) ? exp(v2 - m) : 0.0;
                double s = e1 + e2;
#pragma unroll
                for (int off = 32; off > 0; off >>= 1)
                    s += __shfl_xor(s, off);
                double inv = 1.0 / s;
                dSc[h * NN + kA] = e1 * inv;
                if (kB < NN) dSc[h * NN + kB] = e2 * inv;
            }
            __syncthreads();
            // F4: z[g][h] = sum_k w[h][k] emb[k][g]
            for (int idx = tid; idx < 1024; idx += 512) {
                int g = idx >> 3, h = idx & 7;
                double z = 0.0;
                for (int k = 0; k < NN; ++k)
                    z += dSc[h * NN + k] * (double)emb[(size_t)k * E_ + g];
                dUZ[idx] = z;
            }
            __syncthreads();
            // F5: glimpse
            if (tid < E_) {
                int h = tid >> 4;
                double gl = 0.0;
                for (int g = 0; g < E_; ++g)
                    gl += dUZ[g * 8 + h] * (double)Wv[(size_t)g * E_ + tid];
                dGl[tid] = gl;
            }
            __syncthreads();
            // F6: vg = M64 @ glimpse
            if (tid < E_) {
                double v = 0.0;
                for (int e = 0; e < E_; ++e)
                    v += dGl[e] * M64[(size_t)tid * E_ + e];
                dVg[tid] = v;
            }
            __syncthreads();
            // F7: xd[k] (reuse dQ1)
            if (tid < NN) {
                const float* ek = emb + (size_t)tid * E_;
                double x = 0.0;
                for (int g = 0; g < E_; ++g)
                    x += (double)ek[g] * dVg[g];
                dQ1[tid] = x * INVSQED;
            }
            __syncthreads();
            // F8: fp64 argmax + LSE + commit
            if (tid < 64) {
                int kA = tid, kB = tid + 64;
                double x1 = dQ1[kA];
                bool mk1;
                if (kA == 0) mk1 = (sMaskDepot != 0);
                else {
                    int c = kA - 1;
                    bool vis = (c < 64) ? ((sVis0 >> c) & 1ull) : ((sVis1 >> (c - 64)) & 1ull);
                    mk1 = vis || (sDem[c] > sD);
                }
                double x2 = 0.0; bool mk2 = true;
                if (kB < NN) {
                    x2 = dQ1[kB];
                    int c = kB - 1;
                    bool vis = (c < 64) ? ((sVis0 >> c) & 1ull) : ((sVis1 >> (c - 64)) & 1ull);
                    mk2 = vis || (sDem[c] > sD);
                }
                double a1 = mk1 ? -1.0e300 : x1;
                double a2 = (kB < NN && !mk2) ? x2 : -1.0e300;
                double mv; int mi;
                if (a1 >= a2) { mv = a1; mi = kA; } else { mv = a2; mi = kB; }
#pragma unroll
                for (int off = 32; off > 0; off >>= 1) {
                    double ov = __shfl_xor(mv, off);
                    int    oi = __shfl_xor(mi, off);
                    if (ov > mv || (ov == mv && oi < mi)) { mv = ov; mi = oi; }
                }
                double lmax = 10.0 * tanh(mv);
                double l1 = mk1 ? NEGV : 10.0 * tanh(x1);
                double l2 = (kB < NN) ? (mk2 ? NEGV : 10.0 * tanh(x2)) : 0.0;
                double s = exp(l1 - lmax) + ((kB < NN) ? exp(l2 - lmax) : 0.0);
#pragma unroll
                for (int off = 32; off > 0; off >>= 1)
                    s += __shfl_xor(s, off);
                if (tid == 0) {
                    int nxt = mi;
                    sLL += -log(s);
                    bool isdep = (nxt == 0);
                    if (isdep) {
                        sD = 1.0f;
                    } else {
                        int c = nxt - 1;
                        sD = sD - sDem[c];
                        if (c < 64) sVis0 |= (1ull << c);
                        else        sVis1 |= (1ull << (c - 64));
                    }
                    bool allv = (sVis0 == 0xFFFFFFFFFFFFFFFFull) &&
                                (sVis1 == 0x0000000FFFFFFFFFull);
                    sMaskDepot = (isdep && !allv) ? 1 : 0;
                    sPrev = nxt;
                    float cx = sCoord[2 * nxt], cy = sCoord[2 * nxt + 1];
                    double dx = (double)cx - (double)sPosX;
                    double dy = (double)cy - (double)sPosY;
                    sCost += sqrt(dx * dx + dy * dy + 1e-10);
                    sPosX = cx; sPosY = cy;
                    sTrig = 0;
                }
            }
            __syncthreads();
        }
    }

    if (tid == 0) {
        double dx = (double)sCoord[0] - (double)sPosX;
        double dy = (double)sCoord[1] - (double)sPosY;
        out[b]      = (float)(sCost + sqrt(dx * dx + dy * dy + 1e-10));
        out[B_ + b] = (float)sLL;
    }
}

// ---------------------------------------------------------------------------
extern "C" void kernel_launch(void* const* d_in, const int* in_sizes, int n_in,
                              void* d_out, int out_size, void* d_ws, size_t ws_size,
                              hipStream_t stream) {
    const float* depot = (const float*)d_in[0];
    const float* cust  = (const float*)d_in[1];
    const float* dem   = (const float*)d_in[2];
    const float* nemb  = (const float*)d_in[3];
    const float* gemb  = (const float*)d_in[4];
    const float* Wk1   = (const float*)d_in[5];
    const float* Wv    = (const float*)d_in[6];
    const float* Wk2   = (const float*)d_in[7];
    const float* Wqf   = (const float*)d_in[8];
    const float* Wout  = (const float*)d_in[9];
    const float* Wqs   = (const float*)d_in[10];
    float*  out = (float*)d_out;
    double* M64 = (double*)d_ws;                       // 128 KB
    float*  M32 = (float*)((char*)d_ws + 131072);      // 64 KB

    k_weights<<<dim3(128), dim3(128), 0, stream>>>(Wk2, Wout, M64, M32);
    k_decode <<<dim3(B_),  dim3(512), 0, stream>>>(depot, cust, dem, nemb, gemb,
                                                   Wk1, Wv, Wqf, Wqs, M64, M32, out);
}